// Round 19
// baseline (134.584 us; speedup 1.0000x reference)
//
#include <hip/hip_runtime.h>
#include <hip/hip_bf16.h>

#define B_DIM 4
#define S_DIM 2048
#define D_DIM 1024
#define H_DIM 16
#define HD_DIM 64

using bf16 = __hip_bfloat16;
using bf16x8 = __attribute__((ext_vector_type(8))) short;
using f32x4 = __attribute__((ext_vector_type(4))) float;

__device__ inline unsigned short f2bfu(float f) {
    bf16 h = __float2bfloat16(f);
    unsigned short s;
    __builtin_memcpy(&s, &h, 2);
    return s;
}
__device__ inline unsigned int pack2bf(float a, float b) {
    return (unsigned int)f2bfu(a) | ((unsigned int)f2bfu(b) << 16);
}
__device__ inline float exp2_raw(float x) {
    float r;
    asm("v_exp_f32 %0, %1" : "=v"(r) : "v"(x));
    return r;
}

typedef __attribute__((address_space(1))) const void cg_void;
typedef __attribute__((address_space(3))) void lds_void;
__device__ inline void gload_lds16(const void* g, void* l) {
    __builtin_amdgcn_global_load_lds((cg_void*)g, (lds_void*)l, 16, 0, 0);
}

// ---------------------------------------------------------------------------
// Kernel 1: fused prep — x->bf16 + w_qkv^T + w_out^T (one launch). (R17)
// ---------------------------------------------------------------------------
__global__ __launch_bounds__(256) void prep_kernel(const float* __restrict__ x,
                                                   bf16* __restrict__ xb,
                                                   const float* __restrict__ wq,
                                                   bf16* __restrict__ wqT,
                                                   const float* __restrict__ wo,
                                                   bf16* __restrict__ woT) {
    int bid = blockIdx.x;
    int tid = threadIdx.x;
    if (bid < 8192) {
        int i = bid * 256 + tid;
        float4 v = reinterpret_cast<const float4*>(x)[i];
        ushort4 o;
        o.x = f2bfu(v.x); o.y = f2bfu(v.y); o.z = f2bfu(v.z); o.w = f2bfu(v.w);
        reinterpret_cast<ushort4*>(xb)[i] = o;
        return;
    }
    __shared__ float tile[32][33];
    const float* in;
    bf16* out;
    int R, C, bx, by;
    if (bid < 11264) {
        int loc = bid - 8192;
        in = wq; out = wqT; R = D_DIM; C = 3 * D_DIM;
        bx = loc % 96; by = loc / 96;
    } else {
        int loc = bid - 11264;
        in = wo; out = woT; R = D_DIM; C = D_DIM;
        bx = loc % 32; by = loc / 32;
    }
    int tx = tid & 31, ty = tid >> 5;
    int c0 = bx * 32, r0 = by * 32;
#pragma unroll
    for (int i = 0; i < 32; i += 8)
        tile[ty + i][tx] = in[(size_t)(r0 + ty + i) * C + c0 + tx];
    __syncthreads();
#pragma unroll
    for (int i = 0; i < 32; i += 8)
        out[(size_t)(c0 + ty + i) * R + r0 + tx] = __float2bfloat16(tile[tx][ty + i]);
}

// ---------------------------------------------------------------------------
// Shared GEMM decode (256xBN tile, 8 waves, BK=64, XOR swizzle, XCD-grouped).
// ---------------------------------------------------------------------------
#define GEMM_PRE(BN_)                                                          \
    const int K = D_DIM;                                                       \
    int bid3 = blockIdx.x;                                                     \
    int xcd = bid3 & 7;                                                        \
    int inner = bid3 >> 3;                                                     \
    int m0 = (xcd * 4 + (inner & 3)) * 256;                                    \
    int n0 = (inner >> 2) * (BN_);                                             \
    int tid = threadIdx.x;                                                     \
    int lane = tid & 63;                                                       \
    int w = tid >> 6;                                                          \
    int wr = w >> 1, wc = w & 1;                                               \
    int lr = lane & 15, lk = lane >> 4;                                        \
    int r = tid >> 3;                                                          \
    int cs = ((tid & 7) ^ (r & 7)) * 8;                                        \
    int wub = w * 1024;                                                        \
    const int rsw = (lr & 7) << 4;                                             \
    const bf16* Ag = A + (size_t)(m0 + r) * K + cs;                            \
    const bf16* Bg = BT + (size_t)(n0 + r) * K + cs;

// ---------------------------------------------------------------------------
// Kernel 3: QKV GEMM, 256x192 tile, deadline-ordered staging, B depth-2
// (3 B-buffers): per K-step single stage point (ph0) issues A(t+1) then
// B(t+2). B flight = 4 phases (~940cyc >= HBM miss); A = 3 phases (L2-hit).
// vmcnt ladder exact (B=3, A=4 insts): ph0 7 (4 at last), ph1 10/7/0.
// LDS: A 2x32KB @0 | B 3x24KB @65536 = 136KB. grid 512 x 512thr.
// ---------------------------------------------------------------------------
__global__ __launch_bounds__(512, 2) void gemm_qkv_kernel(const bf16* __restrict__ A,
                                                          const bf16* __restrict__ BT,
                                                          const float* __restrict__ bias,
                                                          bf16* __restrict__ Qo,
                                                          bf16* __restrict__ Ko,
                                                          bf16* __restrict__ Vt) {
    __shared__ __align__(16) char smem[139264];
    f32x4 acc[4][6] = {};
    GEMM_PRE(192);

#define QKV_STAGE_A(buf, kt)                                                   \
    do {                                                                       \
        char* d_ = smem + (buf) * 32768 + wub;                                 \
        gload_lds16(Ag + (kt) * 64, d_);                                       \
        gload_lds16(Ag + 64 * 1024 + (kt) * 64, d_ + 8192);                    \
        gload_lds16(Ag + 128 * 1024 + (kt) * 64, d_ + 16384);                  \
        gload_lds16(Ag + 192 * 1024 + (kt) * 64, d_ + 24576);                  \
    } while (0)
#define QKV_STAGE_B(buf, kt)                                                   \
    do {                                                                       \
        char* d_ = smem + 65536 + (buf) * 24576 + wub;                         \
        gload_lds16(Bg + (kt) * 64, d_);                                       \
        gload_lds16(Bg + 64 * 1024 + (kt) * 64, d_ + 8192);                    \
        gload_lds16(Bg + 128 * 1024 + (kt) * 64, d_ + 16384);                  \
    } while (0)

    const int NT = K / 64;  // 16
    // prologue (deadline order): B0, A0, B1
    QKV_STAGE_B(0, 0);
    QKV_STAGE_A(0, 0);
    QKV_STAGE_B(1, 1);

    bf16x8 af0[4], af1[4], bf0[6], bf1[6], pa1[4], pb1[6];
    int bbuf = 0;  // t % 3
    for (int t = 0; t < NT; ++t) {
        char* as = smem + (t & 1) * 32768;
        char* bs = smem + 65536 + bbuf * 24576;
        // ---- ph0: wait B(t); read B frags; stage A(t+1), B(t+2); MFMA[t-1,k1]
        if (t + 1 < NT) asm volatile("s_waitcnt vmcnt(7)" ::: "memory");
        else            asm volatile("s_waitcnt vmcnt(4)" ::: "memory");
        __builtin_amdgcn_s_barrier();
        __builtin_amdgcn_sched_barrier(0);
#pragma unroll
        for (int nf = 0; nf < 6; ++nf) {
            int row = wc * 96 + nf * 16 + lr;
            char* ba = bs + row * 128;
            bf0[nf] = *(const bf16x8*)(ba + ((lk * 16) ^ rsw));
            bf1[nf] = *(const bf16x8*)(ba + ((64 + lk * 16) ^ rsw));
        }
        if (t + 1 < NT) QKV_STAGE_A((t + 1) & 1, t + 1);
        if (t + 2 < NT) {
            int nb = bbuf + 2; if (nb >= 3) nb -= 3;
            QKV_STAGE_B(nb, t + 2);
        }
        if (t) {
            __builtin_amdgcn_s_setprio(1);
#pragma unroll
            for (int mf = 0; mf < 4; ++mf)
#pragma unroll
                for (int nf = 0; nf < 6; ++nf)
                    acc[mf][nf] = __builtin_amdgcn_mfma_f32_16x16x32_bf16(
                        pa1[mf], pb1[nf], acc[mf][nf], 0, 0, 0);
            __builtin_amdgcn_s_setprio(0);
        }
        // ---- ph1: wait A(t); read A frags; MFMA[t,k0]
        if (t + 3 <= NT) {
            if (t + 3 < NT || t + 2 == NT - 1)
                ;  // (handled below by exact ladder)
        }
        if (t <= NT - 3)      asm volatile("s_waitcnt vmcnt(10)" ::: "memory");
        else if (t == NT - 2) asm volatile("s_waitcnt vmcnt(7)" ::: "memory");
        else                  asm volatile("s_waitcnt vmcnt(0)" ::: "memory");
        __builtin_amdgcn_s_barrier();
        __builtin_amdgcn_sched_barrier(0);
#pragma unroll
        for (int mf = 0; mf < 4; ++mf) {
            int row = wr * 64 + mf * 16 + lr;
            char* aa = as + row * 128;
            af0[mf] = *(const bf16x8*)(aa + ((lk * 16) ^ rsw));
            af1[mf] = *(const bf16x8*)(aa + ((64 + lk * 16) ^ rsw));
        }
        __builtin_amdgcn_s_setprio(1);
#pragma unroll
        for (int mf = 0; mf < 4; ++mf)
#pragma unroll
            for (int nf = 0; nf < 6; ++nf)
                acc[mf][nf] = __builtin_amdgcn_mfma_f32_16x16x32_bf16(
                    af0[mf], bf0[nf], acc[mf][nf], 0, 0, 0);
        __builtin_amdgcn_s_setprio(0);
#pragma unroll
        for (int mf = 0; mf < 4; ++mf) pa1[mf] = af1[mf];
#pragma unroll
        for (int nf = 0; nf < 6; ++nf) pb1[nf] = bf1[nf];
        ++bbuf; if (bbuf >= 3) bbuf = 0;
    }
    // tail: k1 of the last K-step
#pragma unroll
    for (int mf = 0; mf < 4; ++mf)
#pragma unroll
        for (int nf = 0; nf < 6; ++nf)
            acc[mf][nf] = __builtin_amdgcn_mfma_f32_16x16x32_bf16(
                pa1[mf], pb1[nf], acc[mf][nf], 0, 0, 0);
#undef QKV_STAGE_A
#undef QKV_STAGE_B

    const float QS = 0.18033688f;  // 0.125 * log2(e)
#pragma unroll
    for (int mf = 0; mf < 4; ++mf) {
        int row = m0 + wr * 64 + mf * 16 + lk * 4;
        int b = row >> 11, s = row & 2047;
#pragma unroll
        for (int nf = 0; nf < 6; ++nf) {
            int cb = n0 + wc * 96 + nf * 16;
            int third = cb >> 10;
            int col = cb + lr;
            int rem = col & 1023;
            int h = rem >> 6, hd = rem & 63;
            float bv = bias[col];
            if (third == 0) {
#pragma unroll
                for (int i = 0; i < 4; ++i)
                    Qo[(((size_t)b * H_DIM + h) * S_DIM + s + i) * HD_DIM + hd] =
                        __float2bfloat16((acc[mf][nf][i] + bv) * QS);
            } else if (third == 1) {
#pragma unroll
                for (int i = 0; i < 4; ++i)
                    Ko[(((size_t)b * H_DIM + h) * S_DIM + s + i) * HD_DIM + hd] =
                        __float2bfloat16(acc[mf][nf][i] + bv);
            } else {
                uint2 d;
                d.x = pack2bf(acc[mf][nf][0] + bv, acc[mf][nf][1] + bv);
                d.y = pack2bf(acc[mf][nf][2] + bv, acc[mf][nf][3] + bv);
                *(uint2*)&Vt[(((size_t)b * H_DIM + h) * HD_DIM + hd) * S_DIM + s] = d;
            }
        }
    }
}

// ---------------------------------------------------------------------------
// Kernel 4: causal flash attention — R15/R17 EXACTLY (best measured).
// ---------------------------------------------------------------------------
__global__ __launch_bounds__(256, 4) void attn_kernel(const bf16* __restrict__ Q,
                                                      const bf16* __restrict__ K,
                                                      const bf16* __restrict__ Vt,
                                                      bf16* __restrict__ Aout) {
    __shared__ __align__(16) char smem[40960];
    int bid = blockIdx.x;
    int bh = bid & 63;
    const int st_tbl[16] = {15, 14, 13, 12, 8, 9, 10, 11, 4, 5, 6, 7, 3, 2, 1, 0};
    int st = st_tbl[bid >> 6];
    int b = bh >> 4, h = bh & 15;
    int w = threadIdx.x >> 6;
    int lane = threadIdx.x & 63;
    int lr = lane & 15, lk = lane >> 4;

    const short* Qs = (const short*)(Q + (size_t)bh * S_DIM * HD_DIM);
    const short* Ks = (const short*)(K + (size_t)bh * S_DIM * HD_DIM);
    const short* Vs = (const short*)(Vt + (size_t)bh * HD_DIM * S_DIM);
    char* pb = smem + 32768 + w * 2048;
    const int sw = (lr & 7) << 4;

    int srow = w * 8 + (lane >> 3);
    int sblk = ((lane & 7) ^ (lane >> 3)) * 8;
    int wub = w * 1024;

    int q0w = st * 128 + w * 32;
    int nt = 2 * st + 2;
    int twl = 2 * st + ((w >> 1) & 1);

    bf16x8 qf[2][2];
#pragma unroll
    for (int qg = 0; qg < 2; ++qg)
#pragma unroll
        for (int c = 0; c < 2; ++c)
            qf[qg][c] = *(const bf16x8*)&Qs[(size_t)(q0w + qg * 16 + lr) * 64 + c * 32 + lk * 8];

    bf16x8 onesv;
#pragma unroll
    for (int z = 0; z < 8; ++z) onesv[z] = (short)0x3F80;

    f32x4 o[4][2] = {};
    f32x4 ol[2] = {};

    gload_lds16(Ks + (size_t)srow * 64 + sblk, smem + wub);
    gload_lds16(Ks + (size_t)(32 + srow) * 64 + sblk, smem + 4096 + wub);
    gload_lds16(Vs + (size_t)srow * S_DIM + sblk, smem + 16384 + wub);
    gload_lds16(Vs + (size_t)(32 + srow) * S_DIM + sblk, smem + 20480 + wub);

    for (int t = 0; t < nt; ++t) {
        int cur = t & 1;
        int kv0 = t * 64;
        __syncthreads();
        if (t + 1 < nt) {
            int kn = kv0 + 64;
            char* kd = smem + (cur ^ 1) * 8192;
            char* vd = smem + 16384 + (cur ^ 1) * 8192;
            gload_lds16(Ks + (size_t)(kn + srow) * 64 + sblk, kd + wub);
            gload_lds16(Ks + (size_t)(kn + 32 + srow) * 64 + sblk, kd + 4096 + wub);
            gload_lds16(Vs + (size_t)srow * S_DIM + kn + sblk, vd + wub);
            gload_lds16(Vs + (size_t)(32 + srow) * S_DIM + kn + sblk, vd + 4096 + wub);
        }
        if (t > twl) continue;
        char* kt = smem + cur * 8192;
        char* vt = smem + 16384 + cur * 8192;
        bool diag = (t == twl);
        int mhi = diag ? ((w & 1) ? 4 : 2) : 4;

        f32x4 s[4][2] = {};
        __builtin_amdgcn_s_setprio(1);
#pragma unroll
        for (int m = 0; m < 4; ++m) {
            if (m >= mhi) continue;
            int rb = (m * 16 + lr) * 128;
            bf16x8 ka = *(const bf16x8*)(kt + rb + ((lk * 16) ^ sw));
            bf16x8 kb2 = *(const bf16x8*)(kt + rb + ((64 + lk * 16) ^ sw));
            s[m][0] = __builtin_amdgcn_mfma_f32_16x16x32_bf16(ka, qf[0][0], s[m][0], 0, 0, 0);
            s[m][0] = __builtin_amdgcn_mfma_f32_16x16x32_bf16(kb2, qf[0][1], s[m][0], 0, 0, 0);
            s[m][1] = __builtin_amdgcn_mfma_f32_16x16x32_bf16(ka, qf[1][0], s[m][1], 0, 0, 0);
            s[m][1] = __builtin_amdgcn_mfma_f32_16x16x32_bf16(kb2, qf[1][1], s[m][1], 0, 0, 0);
        }
        __builtin_amdgcn_s_setprio(0);

        if (kv0 + 63 > q0w) {
#pragma unroll
            for (int m = 0; m < 4; ++m)
#pragma unroll
                for (int qg = 0; qg < 2; ++qg) {
                    int qq = q0w + qg * 16 + lr;
#pragma unroll
                    for (int i = 0; i < 4; ++i)
                        if (kv0 + m * 16 + lk * 4 + i > qq) s[m][qg][i] = -1e30f;
                }
        }

#pragma unroll
        for (int m = 0; m < 4; ++m)
#pragma unroll
            for (int qg = 0; qg < 2; ++qg)
#pragma unroll
                for (int i = 0; i < 4; ++i) s[m][qg][i] = exp2_raw(s[m][qg][i]);

        bf16x8 pf[2][2];
#pragma unroll
        for (int qg = 0; qg < 2; ++qg) {
#pragma unroll
            for (int m = 0; m < 4; ++m) {
                uint2 d;
                d.x = pack2bf(s[m][qg][0], s[m][qg][1]);
                d.y = pack2bf(s[m][qg][2], s[m][qg][3]);
                *(uint2*)(pb + lr * 128 + ((m * 32 + lk * 8) ^ sw)) = d;
            }
            pf[qg][0] = *(const bf16x8*)(pb + lr * 128 + ((lk * 16) ^ sw));
            pf[qg][1] = *(const bf16x8*)(pb + lr * 128 + ((64 + lk * 16) ^ sw));
        }

        __builtin_amdgcn_s_setprio(1);
#pragma unroll
        for (int m = 0; m < 4; ++m) {
            int rb = (m * 16 + lr) * 128;
            bf16x8 va = *(const bf16x8*)(vt + rb + ((lk * 16) ^ sw));
            bf16x8 vb2 = *(const bf16x8*)(vt + rb + ((64 + lk * 16) ^ sw));
            o[m][0] = __builtin_amdgcn_mfma_f32_16x16x32_bf16(va, pf[0][0], o[m][0], 0, 0, 0);
            o[m][0] = __builtin_amdgcn_mfma_f32_16x16x32_bf16(vb2, pf[0][1], o[m][0], 0, 0, 0);
            o[m][1] = __builtin_amdgcn_mfma_f32_16x16x32_bf16(va, pf[1][0], o[m][1], 0, 0, 0);
            o[m][1] = __builtin_amdgcn_mfma_f32_16x16x32_bf16(vb2, pf[1][1], o[m][1], 0, 0, 0);
        }
        ol[0] = __builtin_amdgcn_mfma_f32_16x16x32_bf16(onesv, pf[0][0], ol[0], 0, 0, 0);
        ol[0] = __builtin_amdgcn_mfma_f32_16x16x32_bf16(onesv, pf[0][1], ol[0], 0, 0, 0);
        ol[1] = __builtin_amdgcn_mfma_f32_16x16x32_bf16(onesv, pf[1][0], ol[1], 0, 0, 0);
        ol[1] = __builtin_amdgcn_mfma_f32_16x16x32_bf16(onesv, pf[1][1], ol[1], 0, 0, 0);
        __builtin_amdgcn_s_setprio(0);
    }

    short* op = (short*)Aout;
#pragma unroll
    for (int qg = 0; qg < 2; ++qg) {
        float inv = 1.0f / ol[qg][0];
        size_t orow = ((size_t)b * S_DIM + q0w + qg * 16 + lr) * D_DIM + h * 64;
#pragma unroll
        for (int m = 0; m < 4; ++m) {
            uint2 d;
            d.x = pack2bf(o[m][qg][0] * inv, o[m][qg][1] * inv);
            d.y = pack2bf(o[m][qg][2] * inv, o[m][qg][3] * inv);
            *(uint2*)(op + orow + m * 16 + lk * 4) = d;
        }
    }
}

// ---------------------------------------------------------------------------
// Kernel 5: output projection GEMM — R18 structure (256x128, 2-phase,
// counted vmcnt), grid 256 x 512thr (1 round).
// ---------------------------------------------------------------------------
__global__ __launch_bounds__(512, 2) void gemm_out_kernel(const bf16* __restrict__ A,
                                                          const bf16* __restrict__ BT,
                                                          const float* __restrict__ bias,
                                                          float* __restrict__ Out) {
    __shared__ __align__(16) char smem[98304];  // 2 x (A 32KB + B 16KB)
    f32x4 acc[4][4] = {};
    GEMM_PRE(128);

#define OUT_STAGE_A(buf, kt)                                                   \
    do {                                                                       \
        char* d_ = smem + (buf) * 49152 + wub;                                 \
        gload_lds16(Ag + (kt) * 64, d_);                                       \
        gload_lds16(Ag + 64 * 1024 + (kt) * 64, d_ + 8192);                    \
        gload_lds16(Ag + 128 * 1024 + (kt) * 64, d_ + 16384);                  \
        gload_lds16(Ag + 192 * 1024 + (kt) * 64, d_ + 24576);                  \
    } while (0)
#define OUT_STAGE_B(buf, kt)                                                   \
    do {                                                                       \
        char* d_ = smem + (buf) * 49152 + 32768 + wub;                         \
        gload_lds16(Bg + (kt) * 64, d_);                                       \
        gload_lds16(Bg + 64 * 1024 + (kt) * 64, d_ + 8192);                    \
    } while (0)

    const int NT = K / 64;  // 16
    OUT_STAGE_B(0, 0);
    OUT_STAGE_A(0, 0);
    bf16x8 af0[4], af1[4], bf0[4], bf1[4], pa1[4], pb1[4];
    for (int t = 0; t < NT; ++t) {
        char* bufb = smem + (t & 1) * 49152;
        asm volatile("s_waitcnt vmcnt(4)" ::: "memory");
        __builtin_amdgcn_s_barrier();
        __builtin_amdgcn_sched_barrier(0);
#pragma unroll
        for (int nf = 0; nf < 4; ++nf) {
            int row = wc * 64 + nf * 16 + lr;
            char* ba = bufb + 32768 + row * 128;
            bf0[nf] = *(const bf16x8*)(ba + ((lk * 16) ^ rsw));
            bf1[nf] = *(const bf16x8*)(ba + ((64 + lk * 16) ^ rsw));
        }
        if (t + 1 < NT) OUT_STAGE_B((t + 1) & 1, t + 1);
        if (t) {
            __builtin_amdgcn_s_setprio(1);
#pragma unroll
            for (int mf = 0; mf < 4; ++mf)
#pragma unroll
                for (int nf = 0; nf < 4; ++nf)
                    acc[mf][nf] = __builtin_amdgcn_mfma_f32_16x16x32_bf16(
                        pa1[mf], pb1[nf], acc[mf][nf], 0, 0, 0);
            __builtin_amdgcn_s_setprio(0);
        }
        if (t + 1 < NT) asm volatile("s_waitcnt vmcnt(2)" ::: "memory");
        else            asm volatile("s_waitcnt vmcnt(0)" ::: "memory");
        __builtin_amdgcn_s_barrier();
        __builtin_amdgcn_sched_barrier(0);
#pragma unroll
        for (int mf = 0; mf < 4; ++mf) {
            int row = wr * 64 + mf * 16 + lr;
            char* aa = bufb + row * 128;
            af0[mf] = *(const bf16x8*)(aa + ((lk * 16) ^ rsw));
            af1[mf] = *(const bf16x8*)(aa + ((64 + lk * 16) ^ rsw));
        }
        if (t + 1 < NT) OUT_STAGE_A((t + 1) & 1, t + 1);
        __builtin_amdgcn_s_setprio(1);
#pragma unroll
        for (int mf = 0; mf < 4; ++mf)
#pragma unroll
            for (int nf = 0; nf < 4; ++nf)
                acc[mf][nf] = __builtin_amdgcn_mfma_f32_16x16x32_bf16(
                    af0[mf], bf0[nf], acc[mf][nf], 0, 0, 0);
        __builtin_amdgcn_s_setprio(0);
#pragma unroll
        for (int mf = 0; mf < 4; ++mf) pa1[mf] = af1[mf];
#pragma unroll
        for (int nf = 0; nf < 4; ++nf) pb1[nf] = bf1[nf];
    }
#pragma unroll
    for (int mf = 0; mf < 4; ++mf)
#pragma unroll
        for (int nf = 0; nf < 4; ++nf)
            acc[mf][nf] = __builtin_amdgcn_mfma_f32_16x16x32_bf16(
                pa1[mf], pb1[nf], acc[mf][nf], 0, 0, 0);
#undef OUT_STAGE_A
#undef OUT_STAGE_B

#pragma unroll
    for (int mf = 0; mf < 4; ++mf) {
        int row = m0 + wr * 64 + mf * 16 + lk * 4;
#pragma unroll
        for (int nf = 0; nf < 4; ++nf) {
            int col = n0 + wc * 64 + nf * 16 + lr;
            float bv = bias[col];
#pragma unroll
            for (int i = 0; i < 4; ++i)
                Out[(size_t)(row + i) * D_DIM + col] = acc[mf][nf][i] + bv;
        }
    }
}

// ---------------------------------------------------------------------------
extern "C" void kernel_launch(void* const* d_in, const int* in_sizes, int n_in,
                              void* d_out, int out_size, void* d_ws, size_t ws_size,
                              hipStream_t stream) {
    const float* x = (const float*)d_in[0];      // [4,2048,1024]
    const float* w_qkv = (const float*)d_in[1];  // [1024,3072]
    const float* b_qkv = (const float*)d_in[2];  // [3072]
    const float* w_out = (const float*)d_in[3];  // [1024,1024]
    const float* b_out = (const float*)d_in[4];  // [1024]
    float* out = (float*)d_out;                  // [4,2048,1024] fp32

    char* ws = (char*)d_ws;
    const size_t SZ_X = (size_t)B_DIM * S_DIM * D_DIM * 2;     // 16.78 MB
    const size_t SZ_WQKV = (size_t)D_DIM * 3 * D_DIM * 2;      // 6.29 MB
    const size_t SZ_WOUT = (size_t)D_DIM * D_DIM * 2;          // 2.10 MB
    bf16* xb = (bf16*)(ws);                      // x bf16; reused as attn output
    bf16* wqkvT = (bf16*)(ws + SZ_X);
    bf16* woutT = (bf16*)(ws + SZ_X + SZ_WQKV);
    bf16* Qb = (bf16*)(ws + SZ_X + SZ_WQKV + SZ_WOUT);
    bf16* Kb = (bf16*)(ws + SZ_X + SZ_WQKV + SZ_WOUT + SZ_X);
    bf16* Vtb = (bf16*)(ws + SZ_X + SZ_WQKV + SZ_WOUT + 2 * SZ_X);

    prep_kernel<<<12288, 256, 0, stream>>>(x, xb, w_qkv, wqkvT, w_out, woutT);
    gemm_qkv_kernel<<<512, 512, 0, stream>>>(xb, wqkvT, b_qkv, Qb, Kb, Vtb);
    attn_kernel<<<dim3(B_DIM * H_DIM * 16), 256, 0, stream>>>(Qb, Kb, Vtb, xb);
    gemm_out_kernel<<<256, 512, 0, stream>>>(xb, woutT, b_out, out);
}

// Round 20
// 130.261 us; speedup vs baseline: 1.0332x; 1.0332x over previous
//
#include <hip/hip_runtime.h>
#include <hip/hip_bf16.h>

#define B_DIM 4
#define S_DIM 2048
#define D_DIM 1024
#define H_DIM 16
#define HD_DIM 64

using bf16 = __hip_bfloat16;
using bf16x8 = __attribute__((ext_vector_type(8))) short;
using f32x4 = __attribute__((ext_vector_type(4))) float;

__device__ inline unsigned short f2bfu(float f) {
    bf16 h = __float2bfloat16(f);
    unsigned short s;
    __builtin_memcpy(&s, &h, 2);
    return s;
}
__device__ inline unsigned int pack2bf(float a, float b) {
    return (unsigned int)f2bfu(a) | ((unsigned int)f2bfu(b) << 16);
}
__device__ inline float exp2_raw(float x) {
    float r;
    asm("v_exp_f32 %0, %1" : "=v"(r) : "v"(x));
    return r;
}

typedef __attribute__((address_space(1))) const void cg_void;
typedef __attribute__((address_space(3))) void lds_void;
__device__ inline void gload_lds16(const void* g, void* l) {
    __builtin_amdgcn_global_load_lds((cg_void*)g, (lds_void*)l, 16, 0, 0);
}

// ---------------------------------------------------------------------------
// Kernel 1: fused prep — x->bf16 + w_qkv^T + w_out^T (one launch). (R17)
// ---------------------------------------------------------------------------
__global__ __launch_bounds__(256) void prep_kernel(const float* __restrict__ x,
                                                   bf16* __restrict__ xb,
                                                   const float* __restrict__ wq,
                                                   bf16* __restrict__ wqT,
                                                   const float* __restrict__ wo,
                                                   bf16* __restrict__ woT) {
    int bid = blockIdx.x;
    int tid = threadIdx.x;
    if (bid < 8192) {
        int i = bid * 256 + tid;
        float4 v = reinterpret_cast<const float4*>(x)[i];
        ushort4 o;
        o.x = f2bfu(v.x); o.y = f2bfu(v.y); o.z = f2bfu(v.z); o.w = f2bfu(v.w);
        reinterpret_cast<ushort4*>(xb)[i] = o;
        return;
    }
    __shared__ float tile[32][33];
    const float* in;
    bf16* out;
    int R, C, bx, by;
    if (bid < 11264) {
        int loc = bid - 8192;
        in = wq; out = wqT; R = D_DIM; C = 3 * D_DIM;
        bx = loc % 96; by = loc / 96;
    } else {
        int loc = bid - 11264;
        in = wo; out = woT; R = D_DIM; C = D_DIM;
        bx = loc % 32; by = loc / 32;
    }
    int tx = tid & 31, ty = tid >> 5;
    int c0 = bx * 32, r0 = by * 32;
#pragma unroll
    for (int i = 0; i < 32; i += 8)
        tile[ty + i][tx] = in[(size_t)(r0 + ty + i) * C + c0 + tx];
    __syncthreads();
#pragma unroll
    for (int i = 0; i < 32; i += 8)
        out[(size_t)(c0 + ty + i) * R + r0 + tx] = __float2bfloat16(tile[tx][ty + i]);
}

// ---------------------------------------------------------------------------
// Big-tile GEMM (R18, best measured): 256xBN tile, 8 waves (512 thr), BK=64,
// XOR swizzle (0 bank conflicts), 2-phase counted-vmcnt pipeline, XCD-grouped
// block decode.
// ---------------------------------------------------------------------------
#define GEMM_PRE(BN_)                                                          \
    const int K = D_DIM;                                                       \
    int bid3 = blockIdx.x;                                                     \
    int xcd = bid3 & 7;                                                        \
    int inner = bid3 >> 3;                                                     \
    int m0 = (xcd * 4 + (inner & 3)) * 256;                                    \
    int n0 = (inner >> 2) * (BN_);                                             \
    int tid = threadIdx.x;                                                     \
    int lane = tid & 63;                                                       \
    int w = tid >> 6;                                                          \
    int wr = w >> 1, wc = w & 1;                                               \
    int lr = lane & 15, lk = lane >> 4;                                        \
    int r = tid >> 3;                                                          \
    int cs = ((tid & 7) ^ (r & 7)) * 8;                                        \
    int wub = w * 1024;                                                        \
    const int rsw = (lr & 7) << 4;                                             \
    const bf16* Ag = A + (size_t)(m0 + r) * K + cs;                            \
    const bf16* Bg = BT + (size_t)(n0 + r) * K + cs;

#define STAGE_A4(buf, kt, BUF_)                                                \
    do {                                                                       \
        char* d_ = smem + (buf) * (BUF_) + wub;                                \
        gload_lds16(Ag + (kt) * 64, d_);                                       \
        gload_lds16(Ag + 64 * 1024 + (kt) * 64, d_ + 8192);                    \
        gload_lds16(Ag + 128 * 1024 + (kt) * 64, d_ + 16384);                  \
        gload_lds16(Ag + 192 * 1024 + (kt) * 64, d_ + 24576);                  \
    } while (0)

#define STAGE_B3(buf, kt, BUF_)                                                \
    do {                                                                       \
        char* d_ = smem + (buf) * (BUF_) + 32768 + wub;                        \
        gload_lds16(Bg + (kt) * 64, d_);                                       \
        gload_lds16(Bg + 64 * 1024 + (kt) * 64, d_ + 8192);                    \
        gload_lds16(Bg + 128 * 1024 + (kt) * 64, d_ + 16384);                  \
    } while (0)

#define STAGE_B2(buf, kt, BUF_)                                                \
    do {                                                                       \
        char* d_ = smem + (buf) * (BUF_) + 32768 + wub;                        \
        gload_lds16(Bg + (kt) * 64, d_);                                       \
        gload_lds16(Bg + 64 * 1024 + (kt) * 64, d_ + 8192);                    \
    } while (0)

#define GEMM_MAIN(NF_, STAGE_B_, BUF_, W0_, W1_)                               \
    const int NT = K / 64; /* 16 */                                            \
    STAGE_B_(0, 0, BUF_);                                                      \
    STAGE_A4(0, 0, BUF_);                                                      \
    bf16x8 af0[4], af1[4], bf0[NF_], bf1[NF_], pa1[4], pb1[NF_];               \
    for (int t = 0; t < NT; ++t) {                                             \
        char* bufb = smem + (t & 1) * (BUF_);                                  \
        asm volatile("s_waitcnt " W0_ ::: "memory");                           \
        __builtin_amdgcn_s_barrier();                                          \
        __builtin_amdgcn_sched_barrier(0);                                     \
        _Pragma("unroll")                                                      \
        for (int nf = 0; nf < NF_; ++nf) {                                     \
            int row = wc * (NF_ * 16) + nf * 16 + lr;                          \
            char* ba = bufb + 32768 + row * 128;                               \
            bf0[nf] = *(const bf16x8*)(ba + ((lk * 16) ^ rsw));                \
            bf1[nf] = *(const bf16x8*)(ba + ((64 + lk * 16) ^ rsw));           \
        }                                                                      \
        if (t + 1 < NT) STAGE_B_((t + 1) & 1, t + 1, BUF_);                    \
        if (t) {                                                               \
            __builtin_amdgcn_s_setprio(1);                                     \
            _Pragma("unroll")                                                  \
            for (int mf = 0; mf < 4; ++mf)                                     \
                _Pragma("unroll")                                              \
                for (int nf = 0; nf < NF_; ++nf)                               \
                    acc[mf][nf] = __builtin_amdgcn_mfma_f32_16x16x32_bf16(     \
                        pa1[mf], pb1[nf], acc[mf][nf], 0, 0, 0);               \
            __builtin_amdgcn_s_setprio(0);                                     \
        }                                                                      \
        if (t + 1 < NT) asm volatile("s_waitcnt " W1_ ::: "memory");           \
        else            asm volatile("s_waitcnt vmcnt(0)" ::: "memory");       \
        __builtin_amdgcn_s_barrier();                                          \
        __builtin_amdgcn_sched_barrier(0);                                     \
        _Pragma("unroll")                                                      \
        for (int mf = 0; mf < 4; ++mf) {                                       \
            int row = wr * 64 + mf * 16 + lr;                                  \
            char* aa = bufb + row * 128;                                       \
            af0[mf] = *(const bf16x8*)(aa + ((lk * 16) ^ rsw));                \
            af1[mf] = *(const bf16x8*)(aa + ((64 + lk * 16) ^ rsw));           \
        }                                                                      \
        if (t + 1 < NT) STAGE_A4((t + 1) & 1, t + 1, BUF_);                    \
        __builtin_amdgcn_s_setprio(1);                                         \
        _Pragma("unroll")                                                      \
        for (int mf = 0; mf < 4; ++mf)                                         \
            _Pragma("unroll")                                                  \
            for (int nf = 0; nf < NF_; ++nf)                                   \
                acc[mf][nf] = __builtin_amdgcn_mfma_f32_16x16x32_bf16(         \
                    af0[mf], bf0[nf], acc[mf][nf], 0, 0, 0);                   \
        __builtin_amdgcn_s_setprio(0);                                         \
        _Pragma("unroll")                                                      \
        for (int mf = 0; mf < 4; ++mf) pa1[mf] = af1[mf];                      \
        _Pragma("unroll")                                                      \
        for (int nf = 0; nf < NF_; ++nf) pb1[nf] = bf1[nf];                    \
    }                                                                          \
    _Pragma("unroll")                                                          \
    for (int mf = 0; mf < 4; ++mf)                                             \
        _Pragma("unroll")                                                      \
        for (int nf = 0; nf < NF_; ++nf)                                       \
            acc[mf][nf] = __builtin_amdgcn_mfma_f32_16x16x32_bf16(             \
                pa1[mf], pb1[nf], acc[mf][nf], 0, 0, 0);

// ---------------------------------------------------------------------------
// Kernel 3: QKV GEMM, 256x192 tile. grid 512 x 512thr (2 even rounds).
// ---------------------------------------------------------------------------
__global__ __launch_bounds__(512, 2) void gemm_qkv_kernel(const bf16* __restrict__ A,
                                                          const bf16* __restrict__ BT,
                                                          const float* __restrict__ bias,
                                                          bf16* __restrict__ Qo,
                                                          bf16* __restrict__ Ko,
                                                          bf16* __restrict__ Vt) {
    __shared__ __align__(16) char smem[114688];  // 2 x (A 32KB + B 24KB)
    f32x4 acc[4][6] = {};
    GEMM_PRE(192);
    GEMM_MAIN(6, STAGE_B3, 57344, "vmcnt(4)", "vmcnt(3)");
    const float QS = 0.18033688f;  // 0.125 * log2(e)
#pragma unroll
    for (int mf = 0; mf < 4; ++mf) {
        int row = m0 + wr * 64 + mf * 16 + lk * 4;
        int b = row >> 11, s = row & 2047;
#pragma unroll
        for (int nf = 0; nf < 6; ++nf) {
            int cb = n0 + wc * 96 + nf * 16;
            int third = cb >> 10;
            int col = cb + lr;
            int rem = col & 1023;
            int h = rem >> 6, hd = rem & 63;
            float bv = bias[col];
            if (third == 0) {
#pragma unroll
                for (int i = 0; i < 4; ++i)
                    Qo[(((size_t)b * H_DIM + h) * S_DIM + s + i) * HD_DIM + hd] =
                        __float2bfloat16((acc[mf][nf][i] + bv) * QS);
            } else if (third == 1) {
#pragma unroll
                for (int i = 0; i < 4; ++i)
                    Ko[(((size_t)b * H_DIM + h) * S_DIM + s + i) * HD_DIM + hd] =
                        __float2bfloat16(acc[mf][nf][i] + bv);
            } else {
                uint2 d;
                d.x = pack2bf(acc[mf][nf][0] + bv, acc[mf][nf][1] + bv);
                d.y = pack2bf(acc[mf][nf][2] + bv, acc[mf][nf][3] + bv);
                *(uint2*)&Vt[(((size_t)b * H_DIM + h) * HD_DIM + hd) * S_DIM + s] = d;
            }
        }
    }
}

// ---------------------------------------------------------------------------
// Kernel 4: causal flash attention — R15/R17 EXACTLY (best measured).
// ---------------------------------------------------------------------------
__global__ __launch_bounds__(256, 4) void attn_kernel(const bf16* __restrict__ Q,
                                                      const bf16* __restrict__ K,
                                                      const bf16* __restrict__ Vt,
                                                      bf16* __restrict__ Aout) {
    __shared__ __align__(16) char smem[40960];
    int bid = blockIdx.x;
    int bh = bid & 63;
    const int st_tbl[16] = {15, 14, 13, 12, 8, 9, 10, 11, 4, 5, 6, 7, 3, 2, 1, 0};
    int st = st_tbl[bid >> 6];
    int b = bh >> 4, h = bh & 15;
    int w = threadIdx.x >> 6;
    int lane = threadIdx.x & 63;
    int lr = lane & 15, lk = lane >> 4;

    const short* Qs = (const short*)(Q + (size_t)bh * S_DIM * HD_DIM);
    const short* Ks = (const short*)(K + (size_t)bh * S_DIM * HD_DIM);
    const short* Vs = (const short*)(Vt + (size_t)bh * HD_DIM * S_DIM);
    char* pb = smem + 32768 + w * 2048;
    const int sw = (lr & 7) << 4;

    int srow = w * 8 + (lane >> 3);
    int sblk = ((lane & 7) ^ (lane >> 3)) * 8;
    int wub = w * 1024;

    int q0w = st * 128 + w * 32;
    int nt = 2 * st + 2;
    int twl = 2 * st + ((w >> 1) & 1);

    bf16x8 qf[2][2];
#pragma unroll
    for (int qg = 0; qg < 2; ++qg)
#pragma unroll
        for (int c = 0; c < 2; ++c)
            qf[qg][c] = *(const bf16x8*)&Qs[(size_t)(q0w + qg * 16 + lr) * 64 + c * 32 + lk * 8];

    bf16x8 onesv;
#pragma unroll
    for (int z = 0; z < 8; ++z) onesv[z] = (short)0x3F80;

    f32x4 o[4][2] = {};
    f32x4 ol[2] = {};

    gload_lds16(Ks + (size_t)srow * 64 + sblk, smem + wub);
    gload_lds16(Ks + (size_t)(32 + srow) * 64 + sblk, smem + 4096 + wub);
    gload_lds16(Vs + (size_t)srow * S_DIM + sblk, smem + 16384 + wub);
    gload_lds16(Vs + (size_t)(32 + srow) * S_DIM + sblk, smem + 20480 + wub);

    for (int t = 0; t < nt; ++t) {
        int cur = t & 1;
        int kv0 = t * 64;
        __syncthreads();
        if (t + 1 < nt) {
            int kn = kv0 + 64;
            char* kd = smem + (cur ^ 1) * 8192;
            char* vd = smem + 16384 + (cur ^ 1) * 8192;
            gload_lds16(Ks + (size_t)(kn + srow) * 64 + sblk, kd + wub);
            gload_lds16(Ks + (size_t)(kn + 32 + srow) * 64 + sblk, kd + 4096 + wub);
            gload_lds16(Vs + (size_t)srow * S_DIM + kn + sblk, vd + wub);
            gload_lds16(Vs + (size_t)(32 + srow) * S_DIM + kn + sblk, vd + 4096 + wub);
        }
        if (t > twl) continue;
        char* kt = smem + cur * 8192;
        char* vt = smem + 16384 + cur * 8192;
        bool diag = (t == twl);
        int mhi = diag ? ((w & 1) ? 4 : 2) : 4;

        f32x4 s[4][2] = {};
        __builtin_amdgcn_s_setprio(1);
#pragma unroll
        for (int m = 0; m < 4; ++m) {
            if (m >= mhi) continue;
            int rb = (m * 16 + lr) * 128;
            bf16x8 ka = *(const bf16x8*)(kt + rb + ((lk * 16) ^ sw));
            bf16x8 kb2 = *(const bf16x8*)(kt + rb + ((64 + lk * 16) ^ sw));
            s[m][0] = __builtin_amdgcn_mfma_f32_16x16x32_bf16(ka, qf[0][0], s[m][0], 0, 0, 0);
            s[m][0] = __builtin_amdgcn_mfma_f32_16x16x32_bf16(kb2, qf[0][1], s[m][0], 0, 0, 0);
            s[m][1] = __builtin_amdgcn_mfma_f32_16x16x32_bf16(ka, qf[1][0], s[m][1], 0, 0, 0);
            s[m][1] = __builtin_amdgcn_mfma_f32_16x16x32_bf16(kb2, qf[1][1], s[m][1], 0, 0, 0);
        }
        __builtin_amdgcn_s_setprio(0);

        if (kv0 + 63 > q0w) {
#pragma unroll
            for (int m = 0; m < 4; ++m)
#pragma unroll
                for (int qg = 0; qg < 2; ++qg) {
                    int qq = q0w + qg * 16 + lr;
#pragma unroll
                    for (int i = 0; i < 4; ++i)
                        if (kv0 + m * 16 + lk * 4 + i > qq) s[m][qg][i] = -1e30f;
                }
        }

#pragma unroll
        for (int m = 0; m < 4; ++m)
#pragma unroll
            for (int qg = 0; qg < 2; ++qg)
#pragma unroll
                for (int i = 0; i < 4; ++i) s[m][qg][i] = exp2_raw(s[m][qg][i]);

        bf16x8 pf[2][2];
#pragma unroll
        for (int qg = 0; qg < 2; ++qg) {
#pragma unroll
            for (int m = 0; m < 4; ++m) {
                uint2 d;
                d.x = pack2bf(s[m][qg][0], s[m][qg][1]);
                d.y = pack2bf(s[m][qg][2], s[m][qg][3]);
                *(uint2*)(pb + lr * 128 + ((m * 32 + lk * 8) ^ sw)) = d;
            }
            pf[qg][0] = *(const bf16x8*)(pb + lr * 128 + ((lk * 16) ^ sw));
            pf[qg][1] = *(const bf16x8*)(pb + lr * 128 + ((64 + lk * 16) ^ sw));
        }

        __builtin_amdgcn_s_setprio(1);
#pragma unroll
        for (int m = 0; m < 4; ++m) {
            int rb = (m * 16 + lr) * 128;
            bf16x8 va = *(const bf16x8*)(vt + rb + ((lk * 16) ^ sw));
            bf16x8 vb2 = *(const bf16x8*)(vt + rb + ((64 + lk * 16) ^ sw));
            o[m][0] = __builtin_amdgcn_mfma_f32_16x16x32_bf16(va, pf[0][0], o[m][0], 0, 0, 0);
            o[m][0] = __builtin_amdgcn_mfma_f32_16x16x32_bf16(vb2, pf[0][1], o[m][0], 0, 0, 0);
            o[m][1] = __builtin_amdgcn_mfma_f32_16x16x32_bf16(va, pf[1][0], o[m][1], 0, 0, 0);
            o[m][1] = __builtin_amdgcn_mfma_f32_16x16x32_bf16(vb2, pf[1][1], o[m][1], 0, 0, 0);
        }
        ol[0] = __builtin_amdgcn_mfma_f32_16x16x32_bf16(onesv, pf[0][0], ol[0], 0, 0, 0);
        ol[0] = __builtin_amdgcn_mfma_f32_16x16x32_bf16(onesv, pf[0][1], ol[0], 0, 0, 0);
        ol[1] = __builtin_amdgcn_mfma_f32_16x16x32_bf16(onesv, pf[1][0], ol[1], 0, 0, 0);
        ol[1] = __builtin_amdgcn_mfma_f32_16x16x32_bf16(onesv, pf[1][1], ol[1], 0, 0, 0);
        __builtin_amdgcn_s_setprio(0);
    }

    short* op = (short*)Aout;
#pragma unroll
    for (int qg = 0; qg < 2; ++qg) {
        float inv = 1.0f / ol[qg][0];
        size_t orow = ((size_t)b * S_DIM + q0w + qg * 16 + lr) * D_DIM + h * 64;
#pragma unroll
        for (int m = 0; m < 4; ++m) {
            uint2 d;
            d.x = pack2bf(o[m][qg][0] * inv, o[m][qg][1] * inv);
            d.y = pack2bf(o[m][qg][2] * inv, o[m][qg][3] * inv);
            *(uint2*)(op + orow + m * 16 + lk * 4) = d;
        }
    }
}

// ---------------------------------------------------------------------------
// Kernel 5: output projection GEMM, 256x128 tile. grid 256 x 512thr (1 round).
// ---------------------------------------------------------------------------
__global__ __launch_bounds__(512, 2) void gemm_out_kernel(const bf16* __restrict__ A,
                                                          const bf16* __restrict__ BT,
                                                          const float* __restrict__ bias,
                                                          float* __restrict__ Out) {
    __shared__ __align__(16) char smem[98304];  // 2 x (A 32KB + B 16KB)
    f32x4 acc[4][4] = {};
    GEMM_PRE(128);
    GEMM_MAIN(4, STAGE_B2, 49152, "vmcnt(4)", "vmcnt(2)");
#pragma unroll
    for (int mf = 0; mf < 4; ++mf) {
        int row = m0 + wr * 64 + mf * 16 + lk * 4;
#pragma unroll
        for (int nf = 0; nf < 4; ++nf) {
            int col = n0 + wc * 64 + nf * 16 + lr;
            float bv = bias[col];
#pragma unroll
            for (int i = 0; i < 4; ++i)
                Out[(size_t)(row + i) * D_DIM + col] = acc[mf][nf][i] + bv;
        }
    }
}

// ---------------------------------------------------------------------------
extern "C" void kernel_launch(void* const* d_in, const int* in_sizes, int n_in,
                              void* d_out, int out_size, void* d_ws, size_t ws_size,
                              hipStream_t stream) {
    const float* x = (const float*)d_in[0];      // [4,2048,1024]
    const float* w_qkv = (const float*)d_in[1];  // [1024,3072]
    const float* b_qkv = (const float*)d_in[2];  // [3072]
    const float* w_out = (const float*)d_in[3];  // [1024,1024]
    const float* b_out = (const float*)d_in[4];  // [1024]
    float* out = (float*)d_out;                  // [4,2048,1024] fp32

    char* ws = (char*)d_ws;
    const size_t SZ_X = (size_t)B_DIM * S_DIM * D_DIM * 2;     // 16.78 MB
    const size_t SZ_WQKV = (size_t)D_DIM * 3 * D_DIM * 2;      // 6.29 MB
    const size_t SZ_WOUT = (size_t)D_DIM * D_DIM * 2;          // 2.10 MB
    bf16* xb = (bf16*)(ws);                      // x bf16; reused as attn output
    bf16* wqkvT = (bf16*)(ws + SZ_X);
    bf16* woutT = (bf16*)(ws + SZ_X + SZ_WQKV);
    bf16* Qb = (bf16*)(ws + SZ_X + SZ_WQKV + SZ_WOUT);
    bf16* Kb = (bf16*)(ws + SZ_X + SZ_WQKV + SZ_WOUT + SZ_X);
    bf16* Vtb = (bf16*)(ws + SZ_X + SZ_WQKV + SZ_WOUT + 2 * SZ_X);

    // 1) fused prep: x->bf16 + w_qkv^T + w_out^T
    prep_kernel<<<12288, 256, 0, stream>>>(x, xb, w_qkv, wqkvT, w_out, woutT);
    // 2) QKV projection (+bias; Q pre-scaled; V transposed), 256x192 tiles
    gemm_qkv_kernel<<<512, 512, 0, stream>>>(xb, wqkvT, b_qkv, Qb, Kb, Vtb);
    // 3) causal flash attention -> attn bf16 [B,S,D] (reuses xb)
    attn_kernel<<<dim3(B_DIM * H_DIM * 16), 256, 0, stream>>>(Qb, Kb, Vtb, xb);
    // 4) output projection (+bias) -> fp32 d_out, 256x128 tiles
    gemm_out_kernel<<<256, 512, 0, stream>>>(xb, woutT, b_out, out);
}